// Round 14
// baseline (4370.510 us; speedup 1.0000x reference)
//
#include <hip/hip_runtime.h>

__device__ __forceinline__ int swz(int c){ return c + ((c>>5)<<2); }  // bank swizzle

// ---------------------------------------------------------------- encoder
__global__ __launch_bounds__(256) void encoder_kernel(
    const float* __restrict__ xc, const float* __restrict__ yc, const float* __restrict__ xt,
    const float* __restrict__ W1, const float* __restrict__ b1,
    const float* __restrict__ W2, const float* __restrict__ b2,
    float* __restrict__ z)
{
  __shared__ float zin[10];
  __shared__ float hid[256];
  int blk = blockIdx.x; int b = blk>>10; int t = blk & 1023;
  int tid = threadIdx.x;
  if (tid < 10){
    float v;
    if (tid < 8)      v = (t<512) ? xc[((size_t)b*512+t)*8+tid] : xt[((size_t)b*512+(t-512))*8+tid];
    else if (tid==8)  v = (t<512) ? yc[(size_t)b*512+t] : 0.f;
    else              v = (t<512) ? 0.f : 1.f;
    zin[tid]=v;
  }
  __syncthreads();
  float s = b1[tid];
  #pragma unroll
  for (int i=0;i<10;i++) s += zin[i]*W1[i*256+tid];
  hid[tid] = fmaxf(s, 0.f);
  __syncthreads();
  float o = b2[tid];
  for (int j=0;j<256;j++) o += hid[j]*W2[j*256+tid];
  z[((size_t)b*1024+t)*256 + tid] = o;
}

// ---------------------------------------------------------------- layernorm
__global__ __launch_bounds__(256) void ln_fast(const float* __restrict__ z,
    const float* __restrict__ g, const float* __restrict__ be, float* __restrict__ h)
{
  __shared__ float red[256];
  int row = blockIdx.x, tid = threadIdx.x;
  float x = z[(size_t)row*256 + tid];
  red[tid] = x; __syncthreads();
  for (int s=128; s>0; s>>=1){ if (tid<s) red[tid]+=red[tid+s]; __syncthreads(); }
  float mu = red[0] * (1.f/256.f); __syncthreads();
  float d = x - mu;
  red[tid] = d*d; __syncthreads();
  for (int s=128; s>0; s>>=1){ if (tid<s) red[tid]+=red[tid+s]; __syncthreads(); }
  float var = red[0] * (1.f/256.f);
  float r = rsqrtf(var + 1e-5f);
  h[(size_t)row*256+tid] = d*r*g[tid] + be[tid];
}

// ------------------------------------------------- GEMM 128x128, 8x8 micro
template<int EPI>
__global__ __launch_bounds__(256) void gemm_big(
    const float* __restrict__ A, const float* __restrict__ B,
    const float* __restrict__ bias, const float* __restrict__ resid,
    float* __restrict__ out, int N, int K)
{
  __shared__ float As[16][140];
  __shared__ float Bs[16][140];
  const int tid = threadIdx.x;
  const int tx = tid & 15, ty = tid >> 4;
  const int m0 = blockIdx.y*128, n0 = blockIdx.x*128;
  const int am = tid >> 1, ak = (tid & 1) * 8;
  const int bk = tid >> 4, bn = (tid & 15) * 8;
  float acc[8][8] = {};
  for (int kk = 0; kk < K; kk += 16){
    float4 av0 = *(const float4*)&A[(size_t)(m0+am)*K + kk + ak];
    float4 av1 = *(const float4*)&A[(size_t)(m0+am)*K + kk + ak + 4];
    float4 bv0 = *(const float4*)&B[(size_t)(kk+bk)*N + n0 + bn];
    float4 bv1 = *(const float4*)&B[(size_t)(kk+bk)*N + n0 + bn + 4];
    __syncthreads();
    int ams = swz(am);
    As[ak+0][ams]=av0.x; As[ak+1][ams]=av0.y; As[ak+2][ams]=av0.z; As[ak+3][ams]=av0.w;
    As[ak+4][ams]=av1.x; As[ak+5][ams]=av1.y; As[ak+6][ams]=av1.z; As[ak+7][ams]=av1.w;
    *(float4*)&Bs[bk][swz(bn)]   = bv0;
    *(float4*)&Bs[bk][swz(bn+4)] = bv1;
    __syncthreads();
    #pragma unroll
    for (int k=0;k<16;k++){
      float a[8], b[8];
      *(float4*)&a[0] = *(const float4*)&As[k][swz(ty*8)];
      *(float4*)&a[4] = *(const float4*)&As[k][swz(ty*8+4)];
      *(float4*)&b[0] = *(const float4*)&Bs[k][swz(tx*8)];
      *(float4*)&b[4] = *(const float4*)&Bs[k][swz(tx*8+4)];
      #pragma unroll
      for (int i=0;i<8;i++)
        #pragma unroll
        for (int j=0;j<8;j++)
          acc[i][j] += a[i]*b[j];
    }
  }
  const int gc0 = n0 + tx*8;
  float bb[8];
  *(float4*)&bb[0] = *(const float4*)&bias[gc0];
  *(float4*)&bb[4] = *(const float4*)&bias[gc0+4];
  #pragma unroll
  for (int i=0;i<8;i++){
    int gr = m0 + ty*8 + i;
    size_t off = (size_t)gr*N + gc0;
    float v[8];
    #pragma unroll
    for (int j=0;j<8;j++){
      v[j] = acc[i][j] + bb[j];
      if (EPI==1) v[j] = fmaxf(v[j], 0.f);
    }
    if (EPI==2){
      float rv[8];
      *(float4*)&rv[0] = *(const float4*)&resid[off];
      *(float4*)&rv[4] = *(const float4*)&resid[off+4];
      #pragma unroll
      for (int j=0;j<8;j++) v[j] += rv[j];
    }
    *(float4*)&out[off]   = *(float4*)&v[0];
    *(float4*)&out[off+4] = *(float4*)&v[4];
  }
}

// ------------------------------------------------- GEMM 64x128, 4x8 micro
template<int EPI>
__global__ __launch_bounds__(256) void gemm_mid(
    const float* __restrict__ A, const float* __restrict__ B,
    const float* __restrict__ bias, const float* __restrict__ resid,
    float* __restrict__ out, int N, int K)
{
  __shared__ float As[16][68];
  __shared__ float Bs[16][140];
  const int tid = threadIdx.x;
  const int tx = tid & 15, ty = tid >> 4;
  const int m0 = blockIdx.y*64, n0 = blockIdx.x*128;
  const int am = tid >> 2, ak = (tid & 3) * 4;
  const int bk = tid >> 4, bn = (tid & 15) * 8;
  float acc[4][8] = {};
  for (int kk = 0; kk < K; kk += 16){
    float4 av = *(const float4*)&A[(size_t)(m0+am)*K + kk + ak];
    float4 bv0 = *(const float4*)&B[(size_t)(kk+bk)*N + n0 + bn];
    float4 bv1 = *(const float4*)&B[(size_t)(kk+bk)*N + n0 + bn + 4];
    __syncthreads();
    As[ak+0][am]=av.x; As[ak+1][am]=av.y; As[ak+2][am]=av.z; As[ak+3][am]=av.w;
    *(float4*)&Bs[bk][swz(bn)]   = bv0;
    *(float4*)&Bs[bk][swz(bn+4)] = bv1;
    __syncthreads();
    #pragma unroll
    for (int k=0;k<16;k++){
      float a[4], b[8];
      *(float4*)&a[0] = *(const float4*)&As[k][ty*4];
      *(float4*)&b[0] = *(const float4*)&Bs[k][swz(tx*8)];
      *(float4*)&b[4] = *(const float4*)&Bs[k][swz(tx*8+4)];
      #pragma unroll
      for (int i=0;i<4;i++)
        #pragma unroll
        for (int j=0;j<8;j++)
          acc[i][j] += a[i]*b[j];
    }
  }
  const int gc0 = n0 + tx*8;
  float bb[8];
  *(float4*)&bb[0] = *(const float4*)&bias[gc0];
  *(float4*)&bb[4] = *(const float4*)&bias[gc0+4];
  #pragma unroll
  for (int i=0;i<4;i++){
    int gr = m0 + ty*4 + i;
    size_t off = (size_t)gr*N + gc0;
    float v[8];
    #pragma unroll
    for (int j=0;j<8;j++){
      v[j] = acc[i][j] + bb[j];
      if (EPI==1) v[j] = fmaxf(v[j], 0.f);
    }
    if (EPI==2){
      float rv[8];
      *(float4*)&rv[0] = *(const float4*)&resid[off];
      *(float4*)&rv[4] = *(const float4*)&resid[off+4];
      #pragma unroll
      for (int j=0;j<8;j++) v[j] += rv[j];
    }
    *(float4*)&out[off]   = *(float4*)&v[0];
    *(float4*)&out[off+4] = *(float4*)&v[4];
  }
}

// ---------------------------------------------------------------- flash attention
// Block: 32 q rows x 1 head x 1 batch, 256 threads. Thread = (q-pair qp, lane lx):
// S-phase: 2 q x 8 keys vs LDS K-tile (d-major); online softmax via 16-lane shfl;
// P via LDS; PV: key-half split (lx>>3), d4 = (lx&7)*4, V from global (128B lines).
// Target rows (qt>=16, block-uniform) self-attend using register-resident Q.
__global__ __launch_bounds__(256) void attn_flash(
    const float* __restrict__ qkv0, float* __restrict__ hb, int bbase)
{
  __shared__ float Qs[32][36];
  __shared__ float Ks[32][132];
  __shared__ float Ps[32][132];
  const int tid = threadIdx.x;
  const int qt = blockIdx.x;       // 0..31
  const int h  = blockIdx.y;
  const int b  = bbase + blockIdx.z;
  const float* qkvb = qkv0 + (size_t)blockIdx.z*1024*768;
  const int qbase = qt*32;
  const float sc = 0.17677669529663687f;   // 1/sqrt(32)

  { // stage Q tile (32 rows x 32 d)
    int r = tid>>3, dp = (tid&7)*4;
    *(float4*)&Qs[r][dp] = *(const float4*)&qkvb[(size_t)(qbase+r)*768 + h*32 + dp];
  }
  __syncthreads();
  const int qp = tid>>4, lx = tid&15;
  const int k8 = lx*8;
  const int r0 = qp*2, r1 = r0+1;
  float Qr0[32], Qr1[32];
  #pragma unroll
  for (int p=0;p<8;p++){
    float4 t0 = *(const float4*)&Qs[r0][p*4];
    float4 t1 = *(const float4*)&Qs[r1][p*4];
    Qr0[p*4+0]=t0.x*sc; Qr0[p*4+1]=t0.y*sc; Qr0[p*4+2]=t0.z*sc; Qr0[p*4+3]=t0.w*sc;
    Qr1[p*4+0]=t1.x*sc; Qr1[p*4+1]=t1.y*sc; Qr1[p*4+2]=t1.z*sc; Qr1[p*4+3]=t1.w*sc;
  }
  float m0=-1e30f,l0=0.f,m1=-1e30f,l1=0.f;
  float a0[4]={0.f,0.f,0.f,0.f}, a1[4]={0.f,0.f,0.f,0.f};
  const int half = lx>>3, d4 = (lx&7)*4;

  for (int t=0;t<4;t++){
    const int k0 = t*128;
    __syncthreads();                       // prev tile's Ps/Ks readers done
    #pragma unroll
    for (int pass=0;pass<4;pass++){        // stage K tile d-major
      int kr = tid>>1, dbase = (tid&1)*4 + pass*8;
      float4 kv = *(const float4*)&qkvb[(size_t)(k0+kr)*768 + 256 + h*32 + dbase];
      Ks[dbase+0][kr]=kv.x; Ks[dbase+1][kr]=kv.y; Ks[dbase+2][kr]=kv.z; Ks[dbase+3][kr]=kv.w;
    }
    __syncthreads();
    float s0[8]={0,0,0,0,0,0,0,0}, s1[8]={0,0,0,0,0,0,0,0};
    #pragma unroll
    for (int d=0; d<32; d++){
      float kx[8];
      *(float4*)&kx[0] = *(const float4*)&Ks[d][k8];
      *(float4*)&kx[4] = *(const float4*)&Ks[d][k8+4];
      float qv0 = Qr0[d], qv1 = Qr1[d];
      #pragma unroll
      for (int j=0;j<8;j++){ s0[j] += qv0*kx[j]; s1[j] += qv1*kx[j]; }
    }
    // online softmax row 0
    float mt = fmaxf(fmaxf(fmaxf(s0[0],s0[1]),fmaxf(s0[2],s0[3])),
                     fmaxf(fmaxf(s0[4],s0[5]),fmaxf(s0[6],s0[7])));
    #pragma unroll
    for (int off=1; off<16; off<<=1) mt = fmaxf(mt, __shfl_xor(mt, off, 64));
    float mn0 = fmaxf(m0, mt), c0 = __expf(m0-mn0);
    float p0[8]; float ps=0.f;
    #pragma unroll
    for (int j=0;j<8;j++){ p0[j]=__expf(s0[j]-mn0); ps+=p0[j]; }
    #pragma unroll
    for (int off=1; off<16; off<<=1) ps += __shfl_xor(ps, off, 64);
    l0 = l0*c0 + ps; m0 = mn0;
    // online softmax row 1
    mt = fmaxf(fmaxf(fmaxf(s1[0],s1[1]),fmaxf(s1[2],s1[3])),
               fmaxf(fmaxf(s1[4],s1[5]),fmaxf(s1[6],s1[7])));
    #pragma unroll
    for (int off=1; off<16; off<<=1) mt = fmaxf(mt, __shfl_xor(mt, off, 64));
    float mn1 = fmaxf(m1, mt), c1 = __expf(m1-mn1);
    float p1[8]; ps=0.f;
    #pragma unroll
    for (int j=0;j<8;j++){ p1[j]=__expf(s1[j]-mn1); ps+=p1[j]; }
    #pragma unroll
    for (int off=1; off<16; off<<=1) ps += __shfl_xor(ps, off, 64);
    l1 = l1*c1 + ps; m1 = mn1;
    // publish P, rescale acc
    *(float4*)&Ps[r0][k8]   = *(float4*)&p0[0];
    *(float4*)&Ps[r0][k8+4] = *(float4*)&p0[4];
    *(float4*)&Ps[r1][k8]   = *(float4*)&p1[0];
    *(float4*)&Ps[r1][k8+4] = *(float4*)&p1[4];
    #pragma unroll
    for (int i=0;i<4;i++){ a0[i]*=c0; a1[i]*=c1; }
    __syncthreads();
    // PV over this tile's key-half
    const int kb = k0 + half*64;
    #pragma unroll
    for (int k4=0;k4<16;k4++){
      float4 pq0 = *(const float4*)&Ps[r0][half*64 + k4*4];
      float4 pq1 = *(const float4*)&Ps[r1][half*64 + k4*4];
      const float* vb = &qkvb[(size_t)(kb + k4*4)*768 + 512 + h*32 + d4];
      float4 v0 = *(const float4*)&vb[0];
      float4 v1 = *(const float4*)&vb[768];
      float4 v2 = *(const float4*)&vb[1536];
      float4 v3 = *(const float4*)&vb[2304];
      a0[0] += pq0.x*v0.x + pq0.y*v1.x + pq0.z*v2.x + pq0.w*v3.x;
      a0[1] += pq0.x*v0.y + pq0.y*v1.y + pq0.z*v2.y + pq0.w*v3.y;
      a0[2] += pq0.x*v0.z + pq0.y*v1.z + pq0.z*v2.z + pq0.w*v3.z;
      a0[3] += pq0.x*v0.w + pq0.y*v1.w + pq0.z*v2.w + pq0.w*v3.w;
      a1[0] += pq1.x*v0.x + pq1.y*v1.x + pq1.z*v2.x + pq1.w*v3.x;
      a1[1] += pq1.x*v0.y + pq1.y*v1.y + pq1.z*v2.y + pq1.w*v3.y;
      a1[2] += pq1.x*v0.z + pq1.y*v1.z + pq1.z*v2.z + pq1.w*v3.z;
      a1[3] += pq1.x*v0.w + pq1.y*v1.w + pq1.z*v2.w + pq1.w*v3.w;
    }
  }
  // merge key-halves (lanes lx and lx^8 hold partials for same d4)
  #pragma unroll
  for (int i=0;i<4;i++){
    a0[i] += __shfl_xor(a0[i], 8, 64);
    a1[i] += __shfl_xor(a1[i], 8, 64);
  }
  // self-key for target blocks (block-uniform)
  if (qt >= 16){
    int g0 = qbase + r0, g1 = qbase + r1;
    float ss0 = 0.f, ss1 = 0.f;
    const float4* kp0 = (const float4*)&qkvb[(size_t)g0*768 + 256 + h*32];
    const float4* kp1 = (const float4*)&qkvb[(size_t)g1*768 + 256 + h*32];
    #pragma unroll
    for (int p=0;p<8;p++){
      float4 t0 = kp0[p], t1 = kp1[p];
      ss0 += Qr0[p*4+0]*t0.x + Qr0[p*4+1]*t0.y + Qr0[p*4+2]*t0.z + Qr0[p*4+3]*t0.w;
      ss1 += Qr1[p*4+0]*t1.x + Qr1[p*4+1]*t1.y + Qr1[p*4+2]*t1.z + Qr1[p*4+3]*t1.w;
    }
    float mn = fmaxf(m0, ss0), c = __expf(m0-mn), pp = __expf(ss0-mn);
    l0 = l0*c + pp;
    float4 vv = *(const float4*)&qkvb[(size_t)g0*768 + 512 + h*32 + d4];
    a0[0]=a0[0]*c+pp*vv.x; a0[1]=a0[1]*c+pp*vv.y; a0[2]=a0[2]*c+pp*vv.z; a0[3]=a0[3]*c+pp*vv.w;
    mn = fmaxf(m1, ss1); c = __expf(m1-mn); pp = __expf(ss1-mn);
    l1 = l1*c + pp;
    vv = *(const float4*)&qkvb[(size_t)g1*768 + 512 + h*32 + d4];
    a1[0]=a1[0]*c+pp*vv.x; a1[1]=a1[1]*c+pp*vv.y; a1[2]=a1[2]*c+pp*vv.z; a1[3]=a1[3]*c+pp*vv.w;
  }
  if (lx < 8){
    float i0 = 1.f/l0, i1 = 1.f/l1;
    float4 o0, o1;
    o0.x=a0[0]*i0; o0.y=a0[1]*i0; o0.z=a0[2]*i0; o0.w=a0[3]*i0;
    o1.x=a1[0]*i1; o1.y=a1[1]*i1; o1.z=a1[2]*i1; o1.w=a1[3]*i1;
    *(float4*)&hb[((size_t)b*1024 + qbase + r0)*256 + h*32 + d4] = o0;
    *(float4*)&hb[((size_t)b*1024 + qbase + r1)*256 + h*32 + d4] = o1;
  }
}

// ---------------------------------------------------------------- launch
extern "C" void kernel_launch(void* const* d_in, const int* in_sizes, int n_in,
                              void* d_out, int out_size, void* d_ws, size_t ws_size,
                              hipStream_t stream)
{
  (void)in_sizes; (void)n_in; (void)out_size;
  const float* xc   = (const float*)d_in[0];
  const float* yc   = (const float*)d_in[1];
  const float* xt   = (const float*)d_in[2];
  const float* eW1  = (const float*)d_in[3];
  const float* eb1  = (const float*)d_in[4];
  const float* eW2  = (const float*)d_in[5];
  const float* eb2  = (const float*)d_in[6];
  const float* Wqkv = (const float*)d_in[7];
  const float* bqkv = (const float*)d_in[8];
  const float* Wo   = (const float*)d_in[9];
  const float* bo   = (const float*)d_in[10];
  const float* ln1g = (const float*)d_in[11];
  const float* ln1b = (const float*)d_in[12];
  const float* ln2g = (const float*)d_in[13];
  const float* ln2b = (const float*)d_in[14];
  const float* Wff1 = (const float*)d_in[15];
  const float* bff1 = (const float*)d_in[16];
  const float* Wff2 = (const float*)d_in[17];
  const float* bff2 = (const float*)d_in[18];

  float* zf = (float*)d_out;            // residual stream [8][1024][256] f32
  char* ws = (char*)d_ws;
  float* hb      = (float*)(ws);                        // 8 MB (LN out / attn out)
  float* scratch = (float*)(ws + (size_t)8*1024*1024);  // qkv / ffh

  const bool bigws = (ws_size == 0) || (ws_size >= (size_t)33*1024*1024);

  encoder_kernel<<<8192, 256, 0, stream>>>(xc, yc, xt, eW1, eb1, eW2, eb2, zf);

  for (int l=0; l<6; l++){
    const float* Wq = Wqkv + (size_t)l*256*768;
    const float* Wl = Wo   + (size_t)l*256*256;
    const float* W1 = Wff1 + (size_t)l*256*1024;
    const float* W2 = Wff2 + (size_t)l*1024*256;

    ln_fast<<<8192, 256, 0, stream>>>(zf, ln1g+l*256, ln1b+l*256, hb);
    if (bigws){
      gemm_big<0><<<dim3(6,64), 256, 0, stream>>>(hb, Wq, bqkv+l*768,
                                                  nullptr, scratch, 768, 256);
      attn_flash<<<dim3(32,8,8), 256, 0, stream>>>(scratch, hb, 0);
    } else {
      for (int b=0; b<8; b++){
        gemm_big<0><<<dim3(6,8), 256, 0, stream>>>(hb + (size_t)b*1024*256, Wq, bqkv+l*768,
                                                   nullptr, scratch, 768, 256);
        attn_flash<<<dim3(32,8,1), 256, 0, stream>>>(scratch, hb, b);
      }
    }
    gemm_mid<2><<<dim3(2,128), 256, 0, stream>>>(hb, Wl, bo+l*256, zf, zf, 256, 256);

    ln_fast<<<8192, 256, 0, stream>>>(zf, ln2g+l*256, ln2b+l*256, hb);
    if (bigws){
      gemm_big<1><<<dim3(8,64), 256, 0, stream>>>(hb, W1, bff1+l*1024,
                                                  nullptr, scratch, 1024, 256);
      gemm_mid<2><<<dim3(2,128), 256, 0, stream>>>(scratch, W2, bff2+l*256,
                                                   zf, zf, 256, 1024);
    } else {
      for (int c=0; c<4; c++){
        float* hrows = hb + (size_t)c*2048*256;
        float* zrows = zf + (size_t)c*2048*256;
        gemm_big<1><<<dim3(8,16), 256, 0, stream>>>(hrows, W1, bff1+l*1024,
                                                    nullptr, scratch, 1024, 256);
        gemm_mid<2><<<dim3(2,32), 256, 0, stream>>>(scratch, W2, bff2+l*256,
                                                    zrows, zrows, 256, 1024);
      }
    }
  }
}